// Round 2
// baseline (362.896 us; speedup 1.0000x reference)
//
#include <hip/hip_runtime.h>

typedef short v8s __attribute__((ext_vector_type(8)));
typedef float v4f __attribute__((ext_vector_type(4)));

#define BATCH 16
#define NBATCH 128           // 2048 / 16
#define BH 16384             // B*H
#define TBH 33554432         // T*B*H

__device__ __forceinline__ ushort f2bf(float f) {
  // round-to-nearest-even fp32 -> bf16 (inputs finite, no NaN handling needed)
  uint u = __float_as_uint(f);
  u += 0x7FFF + ((u >> 16) & 1);
  return (ushort)(u >> 16);
}

// pack 2 fp32 -> 2 bf16 in one uint via the HW pack-convert (RTNE, matches f2bf)
__device__ __forceinline__ uint pkbf2(float a, float b) {
  uint r;
  asm("v_cvt_pk_bf16_f32 %0, %1, %2" : "=v"(r) : "v"(a), "v"(b));
  return r;
}

union frag_u { uint u[4]; v8s s; };

// ---------------- Phase 1: xW[m,h] = sum_i x[m,i] * W[h,i] ----------------
// 2-phase double-buffered global_load_lds GEMM, W resident in VGPRs:
//   - block = 4 waves, each wave owns a 64-col slice of H; W slice = 32 VGPRs bf16
//   - A staged 16-row x K=256 fp32 chunks via global_load_lds_dwordx4 (DMA, no VALU)
//   - LDS XOR-swizzle (byte ^= (row&7)<<4) via pre-swizzled global source (rule 21):
//     makes the stride-1KB ds_read_b128 bank-uniform (8 lanes per 16B slot)
//   - fp32->bf16 conversion on the LDS->reg side with v_cvt_pk_bf16_f32
//   - 1024 blocks (BM=128, 8 chunks each) -> 4 blocks/CU, 16 waves/CU
__global__ __launch_bounds__(256, 4) void indrnn_gemm(
    const float* __restrict__ A,
    const float* __restrict__ W,
    ushort* __restrict__ C)
{
  __shared__ __align__(16) float sbuf[2][4096];   // 2 x 16KB: [16 rows][256 k] fp32

  const int tid  = threadIdx.x;
  const int lane = tid & 63;
  const int wv   = tid >> 6;       // 0..3 -> 64-col slice of H
  const int l15  = lane & 15;
  const int lhi  = lane >> 4;      // 0..3
  const int c0   = wv * 64;
  const int m0   = blockIdx.x * 128;

  // ---- stage chunk 0 first so the DMA flies under the W-register prologue ----
  {
    const float* base = A + ((size_t)m0 << 8);
    #pragma unroll
    for (int j = 0; j < 4; ++j) {
      const int row = wv * 4 + j;                       // wave-uniform
      const float* src = base + (row << 8) + ((lane ^ (row & 7)) << 2);
      __builtin_amdgcn_global_load_lds(src, &sbuf[0][row << 8], 16, 0, 0);
    }
  }

  // ---- W fragments resident in VGPRs: wfr[nt][kk] (B-frag: lane=col l15, k=lhi*8+j) ----
  frag_u wfr[4][8];
  #pragma unroll
  for (int nt = 0; nt < 4; ++nt) {
    const float* pw = W + (((size_t)(c0 + nt * 16 + l15)) << 8) + (lhi << 3);
    #pragma unroll
    for (int kk = 0; kk < 8; ++kk) {
      const float4 w0 = *(const float4*)(pw + kk * 32);
      const float4 w1 = *(const float4*)(pw + kk * 32 + 4);
      wfr[nt][kk].u[0] = pkbf2(w0.x, w0.y);
      wfr[nt][kk].u[1] = pkbf2(w0.z, w0.w);
      wfr[nt][kk].u[2] = pkbf2(w1.x, w1.y);
      wfr[nt][kk].u[3] = pkbf2(w1.z, w1.w);
    }
  }

  // swizzled LDS read bases (bytes), constant across chunks:
  // logical (row=l15, col byte c) lives at phys = row*1024 + (c ^ ((row&7)<<4))
  const int swm  = (l15 & 7) << 4;
  const int off0 = (l15 << 10) + ((lhi * 32)      ^ swm);
  const int off1 = (l15 << 10) + ((lhi * 32 + 16) ^ swm);

  __syncthreads();   // chunk 0 staged (drains vmcnt)

  for (int c = 0; c < 8; ++c) {
    const int cur = c & 1;

    // ---- issue next chunk's DMA before touching LDS (2-phase overlap) ----
    if (c + 1 < 8) {
      const float* base = A + (((size_t)(m0 + (c + 1) * 16)) << 8);
      #pragma unroll
      for (int j = 0; j < 4; ++j) {
        const int row = wv * 4 + j;
        const float* src = base + (row << 8) + ((lane ^ (row & 7)) << 2);
        __builtin_amdgcn_global_load_lds(src, &sbuf[cur ^ 1][row << 8], 16, 0, 0);
      }
    }

    // ---- compute current chunk: LDS -> cvt_pk -> 32 MFMAs ----
    const char* p0 = (const char*)sbuf[cur] + off0;
    const char* p1 = (const char*)sbuf[cur] + off1;
    v4f acc[4] = {};
    #pragma unroll
    for (int kk = 0; kk < 8; ++kk) {
      const float4 f0 = *(const float4*)(p0 + kk * 128);
      const float4 f1 = *(const float4*)(p1 + kk * 128);
      frag_u af;
      af.u[0] = pkbf2(f0.x, f0.y);
      af.u[1] = pkbf2(f0.z, f0.w);
      af.u[2] = pkbf2(f1.x, f1.y);
      af.u[3] = pkbf2(f1.z, f1.w);
      #pragma unroll
      for (int nt = 0; nt < 4; ++nt)
        acc[nt] = __builtin_amdgcn_mfma_f32_16x16x32_bf16(af.s, wfr[nt][kk].s, acc[nt], 0, 0, 0);
    }

    // ---- epilogue: C/D layout col=lane&15, row=(lane>>4)*4+r ----
    const int mrow = m0 + c * 16 + lhi * 4;
    #pragma unroll
    for (int nt = 0; nt < 4; ++nt) {
      const int col = c0 + nt * 16 + l15;
      #pragma unroll
      for (int r = 0; r < 4; ++r)
        C[(((size_t)(mrow + r)) << 8) + col] = f2bf(acc[nt][r]);
    }

    __syncthreads();   // drains next-chunk DMA; also fences LDS reuse
  }
}

// ---------------- Phase 2: sequential scan, 1 thread per (b,h) channel ----------------
// h_t = relu(xw_t + w * h_{t-1}); out[t*BH + ch] = h_t; out[TBH + ch] = h_last
__global__ __launch_bounds__(64) void indrnn_scan(
    const ushort* __restrict__ xw,
    const float* __restrict__ h0,
    const float* __restrict__ w_hh,
    float* __restrict__ out)
{
  const int ch = blockIdx.x * 64 + threadIdx.x;   // 256 blocks x 64 = 16384 channels
  const float w = w_hh[ch & 255];
  float h = h0[ch];
  const ushort* px = xw + ch;
  float* po = out + ch;

  uint b0[BATCH], b1[BATCH], b2[BATCH], b3[BATCH];

  auto ld = [&](uint (&buf)[BATCH], int kb) {
    const ushort* p = px + (size_t)kb * BATCH * BH;
    #pragma unroll
    for (int j = 0; j < BATCH; ++j) buf[j] = p[(size_t)j * BH];
  };
  auto cp = [&](uint (&buf)[BATCH], int kb) {
    float* o = po + (size_t)kb * BATCH * BH;
    #pragma unroll
    for (int j = 0; j < BATCH; ++j) {
      float xv = __uint_as_float(buf[j] << 16);
      h = fmaxf(fmaf(h, w, xv), 0.0f);
      o[(size_t)j * BH] = h;
    }
  };

  ld(b0, 0); ld(b1, 1); ld(b2, 2); ld(b3, 3);
  for (int kb = 0; kb < NBATCH; kb += 4) {
    cp(b0, kb);     if (kb + 4 < NBATCH) ld(b0, kb + 4);
    cp(b1, kb + 1); if (kb + 5 < NBATCH) ld(b1, kb + 5);
    cp(b2, kb + 2); if (kb + 6 < NBATCH) ld(b2, kb + 6);
    cp(b3, kb + 3); if (kb + 7 < NBATCH) ld(b3, kb + 7);
  }
  out[(size_t)TBH + ch] = h;
}

extern "C" void kernel_launch(void* const* d_in, const int* in_sizes, int n_in,
                              void* d_out, int out_size, void* d_ws, size_t ws_size,
                              hipStream_t stream) {
  const float* x    = (const float*)d_in[0];   // [2048, 64, 256]
  const float* h0   = (const float*)d_in[1];   // [1, 64, 256]
  const float* W_ih = (const float*)d_in[2];   // [256, 256]
  const float* w_hh = (const float*)d_in[3];   // [256]
  float* out = (float*)d_out;                  // [T,B,H] ++ [1,B,H]
  ushort* xw = (ushort*)d_ws;                  // bf16 intermediate, 64 MB

  indrnn_gemm<<<dim3(1024), dim3(256), 0, stream>>>(x, W_ih, xw);
  indrnn_scan<<<dim3(256), dim3(64), 0, stream>>>(xw, h0, w_hh, out);
}

// Round 3
// 298.595 us; speedup vs baseline: 1.2153x; 1.2153x over previous
//
#include <hip/hip_runtime.h>

typedef short v8s __attribute__((ext_vector_type(8)));
typedef float v4f __attribute__((ext_vector_type(4)));

#define BH 16384             // B*H
#define TBH 33554432         // T*B*H
#define SCAN_TILE 128        // timesteps per LDS tile
#define NTILE 16             // 2048 / 128

__device__ __forceinline__ ushort f2bf(float f) {
  // round-to-nearest-even fp32 -> bf16 (inputs finite, no NaN handling needed)
  uint u = __float_as_uint(f);
  u += 0x7FFF + ((u >> 16) & 1);
  return (ushort)(u >> 16);
}

// ---------------- Phase 1: xW[m,h] = sum_i x[m,i] * W[h,i], bf16 MFMA ----------------
// (r0 structure, best measured: 88 us. LDS-staged A and W, 8 waves, BM=128 BN=256.)
__global__ __launch_bounds__(512) void indrnn_gemm(
    const float* __restrict__ A,
    const float* __restrict__ W,
    ushort* __restrict__ C)
{
  // BM=128, BN=256 (full H), BK=64; pad LDS rows 64->72 shorts to break bank conflicts
  __shared__ ushort As[128 * 72];
  __shared__ ushort Bs[256 * 72];

  const int tid  = threadIdx.x;
  const int lane = tid & 63;
  const int wid  = tid >> 6;    // 0..7
  const int wm   = wid >> 2;    // 0..1  (M dim, 64 rows each)
  const int wn   = wid & 3;     // 0..3  (N dim, 64 cols each)
  const int m0   = blockIdx.x * 128;

  const int l15 = lane & 15;
  const int lhi = lane >> 4;    // 0..3

  v4f acc[4][4] = {};

  for (int kc = 0; kc < 4; ++kc) {
    // stage A tile: 128 rows x 64 k (fp32 -> bf16), 2048 float4s over 512 threads
    #pragma unroll
    for (int j = 0; j < 4; ++j) {
      int f    = j * 512 + tid;
      int row  = f >> 4;
      int colf = f & 15;
      const float4 a4 = *(const float4*)(A + ((size_t)(m0 + row) << 8) + kc * 64 + colf * 4);
      ushort4 b4 = make_ushort4(f2bf(a4.x), f2bf(a4.y), f2bf(a4.z), f2bf(a4.w));
      *(ushort4*)(As + row * 72 + colf * 4) = b4;
    }
    // stage B tile (W): 256 rows x 64 k
    #pragma unroll
    for (int j = 0; j < 8; ++j) {
      int f    = j * 512 + tid;
      int row  = f >> 4;
      int colf = f & 15;
      const float4 a4 = *(const float4*)(W + ((size_t)row << 8) + kc * 64 + colf * 4);
      ushort4 b4 = make_ushort4(f2bf(a4.x), f2bf(a4.y), f2bf(a4.z), f2bf(a4.w));
      *(ushort4*)(Bs + row * 72 + colf * 4) = b4;
    }
    __syncthreads();

    #pragma unroll
    for (int kk = 0; kk < 2; ++kk) {
      const int koff = kk * 32 + lhi * 8;
      v8s af[4], bf[4];
      #pragma unroll
      for (int mt = 0; mt < 4; ++mt)
        af[mt] = *(const v8s*)(As + (wm * 64 + mt * 16 + l15) * 72 + koff);
      #pragma unroll
      for (int nt = 0; nt < 4; ++nt)
        bf[nt] = *(const v8s*)(Bs + (wn * 64 + nt * 16 + l15) * 72 + koff);
      #pragma unroll
      for (int mt = 0; mt < 4; ++mt)
        #pragma unroll
        for (int nt = 0; nt < 4; ++nt)
          acc[mt][nt] = __builtin_amdgcn_mfma_f32_16x16x32_bf16(af[mt], bf[nt], acc[mt][nt], 0, 0, 0);
    }
    __syncthreads();
  }

  // epilogue: C/D layout col=lane&15, row=(lane>>4)*4+reg
  #pragma unroll
  for (int mt = 0; mt < 4; ++mt) {
    #pragma unroll
    for (int nt = 0; nt < 4; ++nt) {
      #pragma unroll
      for (int r = 0; r < 4; ++r) {
        int row = m0 + wm * 64 + mt * 16 + lhi * 4 + r;
        int col = wn * 64 + nt * 16 + l15;
        C[((size_t)row << 8) + col] = f2bf(acc[mt][nt][r]);
      }
    }
  }
}

// ---------------- Phase 2: producer-consumer scan ----------------
// 256 blocks x 2 waves; block owns 64 channels.
//   wave 1 (producer): DMA xw tiles [128 t][64 ch] (16 KB) into LDS via
//     global_load_lds_dwordx4, 3-deep pipeline, counted vmcnt(16) (T3+T4).
//     Its vmcnt queue holds ONLY loads.
//   wave 0 (consumer): serial recurrence h = relu(fma(h,w,xv)) out of LDS,
//     streams fp32 stores. Its vmcnt queue holds ONLY stores, never waited on.
__global__ __launch_bounds__(128) void indrnn_scan(
    const ushort* __restrict__ xw,
    const float* __restrict__ h0,
    const float* __restrict__ w_hh,
    float* __restrict__ out)
{
  __shared__ __align__(16) ushort tile[3][SCAN_TILE * 64];   // 3 x 16 KB

  const int lane = threadIdx.x & 63;
  const int wv   = threadIdx.x >> 6;        // 0 = consumer, 1 = producer
  const int ch0  = blockIdx.x * 64;
  const int ch   = ch0 + lane;

  // producer: per-lane global source covers 8 t-rows x 128 B per instruction;
  // LDS dest is linear (uniform base + lane*16) -> row-major [t][ch] tile.
  const size_t psrc0 = (size_t)(lane >> 3) * BH + (size_t)ch0 + ((lane & 7) << 3);

  auto stage = [&](int ti) {
    const ushort* src = xw + (size_t)ti * SCAN_TILE * BH + psrc0;
    ushort* dst = &tile[ti % 3][0];
    #pragma unroll
    for (int j = 0; j < 16; ++j) {
      __builtin_amdgcn_global_load_lds(
          (const float*)(src + (size_t)j * 8 * BH),
          (float*)(dst + j * 512), 16, 0, 0);
    }
  };

  float h = 0.0f, w = 0.0f;
  if (wv == 0) {
    h = h0[ch];
    w = w_hh[ch & 255];
  } else {
    stage(0);
    stage(1);
    asm volatile("s_waitcnt vmcnt(16)" ::: "memory");   // tile 0 complete
  }
  asm volatile("" ::: "memory");
  __builtin_amdgcn_s_barrier();
  __builtin_amdgcn_sched_barrier(0);

  for (int i = 0; i < NTILE; ++i) {
    if (wv == 0) {
      // ---- consume tile i: 128 sequential steps for this lane's channel ----
      const ushort* tp = &tile[i % 3][lane];
      float* po = out + (size_t)i * SCAN_TILE * BH + ch;
      #pragma unroll
      for (int t = 0; t < SCAN_TILE; t += 16) {
        ushort v[16];
        #pragma unroll
        for (int j = 0; j < 16; ++j) v[j] = tp[(t + j) * 64];
        #pragma unroll
        for (int j = 0; j < 16; ++j) {
          float xv = __uint_as_float((uint)v[j] << 16);
          h = fmaxf(fmaf(h, w, xv), 0.0f);
          po[(size_t)(t + j) * BH] = h;
        }
      }
    } else {
      // ---- produce tile i+2; guarantee tile i+1 complete before barrier ----
      if (i + 2 < NTILE) {
        stage(i + 2);
        asm volatile("s_waitcnt vmcnt(16)" ::: "memory");  // tile i+1 done, i+2 in flight
      } else {
        asm volatile("s_waitcnt vmcnt(0)" ::: "memory");   // drain tail
      }
    }
    asm volatile("" ::: "memory");
    __builtin_amdgcn_s_barrier();
    __builtin_amdgcn_sched_barrier(0);
  }

  if (wv == 0) out[(size_t)TBH + ch] = h;
}

extern "C" void kernel_launch(void* const* d_in, const int* in_sizes, int n_in,
                              void* d_out, int out_size, void* d_ws, size_t ws_size,
                              hipStream_t stream) {
  const float* x    = (const float*)d_in[0];   // [2048, 64, 256]
  const float* h0   = (const float*)d_in[1];   // [1, 64, 256]
  const float* W_ih = (const float*)d_in[2];   // [256, 256]
  const float* w_hh = (const float*)d_in[3];   // [256]
  float* out = (float*)d_out;                  // [T,B,H] ++ [1,B,H]
  ushort* xw = (ushort*)d_ws;                  // bf16 intermediate, 64 MB

  indrnn_gemm<<<dim3(1024), dim3(512), 0, stream>>>(x, W_ih, xw);
  indrnn_scan<<<dim3(256), dim3(128), 0, stream>>>(xw, h0, w_hh, out);
}

// Round 4
// 286.140 us; speedup vs baseline: 1.2682x; 1.0435x over previous
//
#include <hip/hip_runtime.h>

typedef short v8s __attribute__((ext_vector_type(8)));
typedef float v4f __attribute__((ext_vector_type(4)));

#define BH 16384             // B*H
#define TBH 33554432         // T*B*H
#define SEG 16               // segments over T
#define SEGT 128             // timesteps per segment (2048/16)
#define SCAN_TILE 128        // (fallback scan) timesteps per LDS tile
#define NTILE 16             // 2048 / 128

__device__ __forceinline__ ushort f2bf(float f) {
  // round-to-nearest-even fp32 -> bf16 (inputs finite, no NaN handling needed)
  uint u = __float_as_uint(f);
  u += 0x7FFF + ((u >> 16) & 1);
  return (ushort)(u >> 16);
}

// ---------------- Phase 1: xW[m,h] = sum_i x[m,i] * W[h,i], bf16 MFMA ----------------
// (r0 structure, best measured: 84-88 us across 3 sessions. FROZEN this round.)
__global__ __launch_bounds__(512) void indrnn_gemm(
    const float* __restrict__ A,
    const float* __restrict__ W,
    ushort* __restrict__ C)
{
  // BM=128, BN=256 (full H), BK=64; pad LDS rows 64->72 shorts to break bank conflicts
  __shared__ ushort As[128 * 72];
  __shared__ ushort Bs[256 * 72];

  const int tid  = threadIdx.x;
  const int lane = tid & 63;
  const int wid  = tid >> 6;    // 0..7
  const int wm   = wid >> 2;    // 0..1  (M dim, 64 rows each)
  const int wn   = wid & 3;     // 0..3  (N dim, 64 cols each)
  const int m0   = blockIdx.x * 128;

  const int l15 = lane & 15;
  const int lhi = lane >> 4;    // 0..3

  v4f acc[4][4] = {};

  for (int kc = 0; kc < 4; ++kc) {
    // stage A tile: 128 rows x 64 k (fp32 -> bf16), 2048 float4s over 512 threads
    #pragma unroll
    for (int j = 0; j < 4; ++j) {
      int f    = j * 512 + tid;
      int row  = f >> 4;
      int colf = f & 15;
      const float4 a4 = *(const float4*)(A + ((size_t)(m0 + row) << 8) + kc * 64 + colf * 4);
      ushort4 b4 = make_ushort4(f2bf(a4.x), f2bf(a4.y), f2bf(a4.z), f2bf(a4.w));
      *(ushort4*)(As + row * 72 + colf * 4) = b4;
    }
    // stage B tile (W): 256 rows x 64 k
    #pragma unroll
    for (int j = 0; j < 8; ++j) {
      int f    = j * 512 + tid;
      int row  = f >> 4;
      int colf = f & 15;
      const float4 a4 = *(const float4*)(W + ((size_t)row << 8) + kc * 64 + colf * 4);
      ushort4 b4 = make_ushort4(f2bf(a4.x), f2bf(a4.y), f2bf(a4.z), f2bf(a4.w));
      *(ushort4*)(Bs + row * 72 + colf * 4) = b4;
    }
    __syncthreads();

    #pragma unroll
    for (int kk = 0; kk < 2; ++kk) {
      const int koff = kk * 32 + lhi * 8;
      v8s af[4], bf[4];
      #pragma unroll
      for (int mt = 0; mt < 4; ++mt)
        af[mt] = *(const v8s*)(As + (wm * 64 + mt * 16 + l15) * 72 + koff);
      #pragma unroll
      for (int nt = 0; nt < 4; ++nt)
        bf[nt] = *(const v8s*)(Bs + (wn * 64 + nt * 16 + l15) * 72 + koff);
      #pragma unroll
      for (int mt = 0; mt < 4; ++mt)
        #pragma unroll
        for (int nt = 0; nt < 4; ++nt)
          acc[mt][nt] = __builtin_amdgcn_mfma_f32_16x16x32_bf16(af[mt], bf[nt], acc[mt][nt], 0, 0, 0);
    }
    __syncthreads();
  }

  // epilogue: C/D layout col=lane&15, row=(lane>>4)*4+reg
  #pragma unroll
  for (int mt = 0; mt < 4; ++mt) {
    #pragma unroll
    for (int nt = 0; nt < 4; ++nt) {
      #pragma unroll
      for (int r = 0; r < 4; ++r) {
        int row = m0 + wm * 64 + mt * 16 + lhi * 4 + r;
        int col = wn * 64 + nt * 16 + l15;
        C[((size_t)row << 8) + col] = f2bf(acc[mt][nt][r]);
      }
    }
  }
}

// ---------------- Phase 2a: per-segment transfer functions ----------------
// IndRNN step f(h)=max(0, x + w*h) preserves the family F(h)=clamp(p*h+a, lo, hi).
// Compose 128 steps per (seg, ch); write (p,a,lo,hi). 1024 blocks -> 16 waves/CU.
__global__ __launch_bounds__(256) void indrnn_seg(
    const ushort* __restrict__ xw,
    const float* __restrict__ w_hh,
    float4* __restrict__ fn)
{
  const int chgrp = blockIdx.x & 63;
  const int seg   = blockIdx.x >> 6;
  const int ch    = chgrp * 256 + threadIdx.x;
  const float w   = w_hh[ch & 255];
  const ushort* px = xw + (size_t)seg * SEGT * BH + ch;

  float p = 1.0f, a = 0.0f, lo = -3.402823466e38f, hi = 3.402823466e38f;

  uint b0[16], b1[16];
  auto ldb = [&](uint (&buf)[16], int kb) {
    const ushort* q = px + (size_t)kb * 16 * BH;
    #pragma unroll
    for (int j = 0; j < 16; ++j) buf[j] = q[(size_t)j * BH];
  };
  auto comp = [&](uint (&buf)[16]) {
    #pragma unroll
    for (int j = 0; j < 16; ++j) {
      float xv = __uint_as_float(buf[j] << 16);
      float A = fmaf(w, lo, xv);
      float B = fmaf(w, hi, xv);
      lo = fmaxf(0.0f, fminf(A, B));
      hi = fmaxf(0.0f, fmaxf(A, B));
      a  = fmaf(w, a, xv);
      p *= w;
    }
  };

  ldb(b0, 0); ldb(b1, 1);
  for (int kb = 0; kb < 8; kb += 2) {
    comp(b0); if (kb + 2 < 8) ldb(b0, kb + 2);
    comp(b1); if (kb + 3 < 8) ldb(b1, kb + 3);
  }
  fn[(size_t)seg * BH + ch] = make_float4(p, a, lo, hi);
}

// ---------------- Phase 2b: prefix-compose h_in, then re-scan + store ----------------
__global__ __launch_bounds__(256) void indrnn_fix(
    const ushort* __restrict__ xw,
    const float* __restrict__ h0,
    const float* __restrict__ w_hh,
    const float4* __restrict__ fn,
    float* __restrict__ out)
{
  const int chgrp = blockIdx.x & 63;
  const int seg   = blockIdx.x >> 6;
  const int ch    = chgrp * 256 + threadIdx.x;
  const float w   = w_hh[ch & 255];

  // exact segment-entry state via <=15 clamp-affine compositions (wave-uniform bound)
  float h = h0[ch];
  for (int s = 0; s < seg; ++s) {
    const float4 F = fn[(size_t)s * BH + ch];
    h = fminf(fmaxf(fmaf(F.x, h, F.y), F.z), F.w);
  }

  const ushort* px = xw + (size_t)seg * SEGT * BH + ch;
  float*        po = out + (size_t)seg * SEGT * BH + ch;

  uint b0[16], b1[16];
  auto ldb = [&](uint (&buf)[16], int kb) {
    const ushort* q = px + (size_t)kb * 16 * BH;
    #pragma unroll
    for (int j = 0; j < 16; ++j) buf[j] = q[(size_t)j * BH];
  };
  auto cp = [&](uint (&buf)[16], int kb) {
    float* o = po + (size_t)kb * 16 * BH;
    #pragma unroll
    for (int j = 0; j < 16; ++j) {
      float xv = __uint_as_float(buf[j] << 16);
      h = fmaxf(fmaf(h, w, xv), 0.0f);
      o[(size_t)j * BH] = h;
    }
  };

  ldb(b0, 0); ldb(b1, 1);
  for (int kb = 0; kb < 8; kb += 2) {
    cp(b0, kb);     if (kb + 2 < 8) ldb(b0, kb + 2);
    cp(b1, kb + 1); if (kb + 3 < 8) ldb(b1, kb + 3);
  }

  if (seg == SEG - 1) out[(size_t)TBH + ch] = h;
}

// ---------------- Fallback scan (r3 producer-consumer) if workspace is tight ----------
__global__ __launch_bounds__(128) void indrnn_scan(
    const ushort* __restrict__ xw,
    const float* __restrict__ h0,
    const float* __restrict__ w_hh,
    float* __restrict__ out)
{
  __shared__ __align__(16) ushort tile[3][SCAN_TILE * 64];   // 3 x 16 KB

  const int lane = threadIdx.x & 63;
  const int wv   = threadIdx.x >> 6;        // 0 = consumer, 1 = producer
  const int ch0  = blockIdx.x * 64;
  const int ch   = ch0 + lane;

  const size_t psrc0 = (size_t)(lane >> 3) * BH + (size_t)ch0 + ((lane & 7) << 3);

  auto stage = [&](int ti) {
    const ushort* src = xw + (size_t)ti * SCAN_TILE * BH + psrc0;
    ushort* dst = &tile[ti % 3][0];
    #pragma unroll
    for (int j = 0; j < 16; ++j) {
      __builtin_amdgcn_global_load_lds(
          (const float*)(src + (size_t)j * 8 * BH),
          (float*)(dst + j * 512), 16, 0, 0);
    }
  };

  float h = 0.0f, w = 0.0f;
  if (wv == 0) {
    h = h0[ch];
    w = w_hh[ch & 255];
  } else {
    stage(0);
    stage(1);
    asm volatile("s_waitcnt vmcnt(16)" ::: "memory");
  }
  asm volatile("" ::: "memory");
  __builtin_amdgcn_s_barrier();
  __builtin_amdgcn_sched_barrier(0);

  for (int i = 0; i < NTILE; ++i) {
    if (wv == 0) {
      const ushort* tp = &tile[i % 3][lane];
      float* po = out + (size_t)i * SCAN_TILE * BH + ch;
      #pragma unroll
      for (int t = 0; t < SCAN_TILE; t += 16) {
        ushort v[16];
        #pragma unroll
        for (int j = 0; j < 16; ++j) v[j] = tp[(t + j) * 64];
        #pragma unroll
        for (int j = 0; j < 16; ++j) {
          float xv = __uint_as_float((uint)v[j] << 16);
          h = fmaxf(fmaf(h, w, xv), 0.0f);
          po[(size_t)(t + j) * BH] = h;
        }
      }
    } else {
      if (i + 2 < NTILE) {
        stage(i + 2);
        asm volatile("s_waitcnt vmcnt(16)" ::: "memory");
      } else {
        asm volatile("s_waitcnt vmcnt(0)" ::: "memory");
      }
    }
    asm volatile("" ::: "memory");
    __builtin_amdgcn_s_barrier();
    __builtin_amdgcn_sched_barrier(0);
  }

  if (wv == 0) out[(size_t)TBH + ch] = h;
}

extern "C" void kernel_launch(void* const* d_in, const int* in_sizes, int n_in,
                              void* d_out, int out_size, void* d_ws, size_t ws_size,
                              hipStream_t stream) {
  const float* x    = (const float*)d_in[0];   // [2048, 64, 256]
  const float* h0   = (const float*)d_in[1];   // [1, 64, 256]
  const float* W_ih = (const float*)d_in[2];   // [256, 256]
  const float* w_hh = (const float*)d_in[3];   // [256]
  float* out = (float*)d_out;                  // [T,B,H] ++ [1,B,H]
  ushort* xw = (ushort*)d_ws;                  // bf16 intermediate, 64 MiB

  indrnn_gemm<<<dim3(1024), dim3(512), 0, stream>>>(x, W_ih, xw);

  const size_t need = (64ull << 20) + (size_t)SEG * BH * sizeof(float4);  // 68 MiB
  if (ws_size >= need) {
    float4* fn = (float4*)((char*)d_ws + (64ull << 20));
    indrnn_seg<<<dim3(1024), dim3(256), 0, stream>>>(xw, w_hh, fn);
    indrnn_fix<<<dim3(1024), dim3(256), 0, stream>>>(xw, h0, w_hh, fn, out);
  } else {
    indrnn_scan<<<dim3(256), dim3(128), 0, stream>>>(xw, h0, w_hh, out);
  }
}

// Round 5
// 281.152 us; speedup vs baseline: 1.2907x; 1.0177x over previous
//
#include <hip/hip_runtime.h>

typedef short v8s __attribute__((ext_vector_type(8)));
typedef float v4f __attribute__((ext_vector_type(4)));

#define BH 16384             // B*H
#define TBH 33554432         // T*B*H
#define SEG 16               // segments over T
#define SEGT 128             // timesteps per segment (2048/16)
#define SCAN_TILE 128        // (fallback scan) timesteps per LDS tile
#define NTILE 16             // 2048 / 128

__device__ __forceinline__ ushort f2bf(float f) {
  // round-to-nearest-even fp32 -> bf16 (inputs finite, no NaN handling needed)
  uint u = __float_as_uint(f);
  u += 0x7FFF + ((u >> 16) & 1);
  return (ushort)(u >> 16);
}

// pack 2 fp32 -> 2 bf16 in one uint via the HW pack-convert (RTNE, matches f2bf)
__device__ __forceinline__ uint pkbf2(float a, float b) {
  uint r;
  asm("v_cvt_pk_bf16_f32 %0, %1, %2" : "=v"(r) : "v"(a), "v"(b));
  return r;
}

union frag_u { uint u[4]; v8s s; };

// ---------------- Phase 0: W fp32 -> bf16, pre-swizzled into DMA-linear layout --------
// Layout: Wbf[kc][row][sp] (16B slots), where slot sp holds logical k-slot sp^(row&7):
// W[row][kc*64 + (sp^(row&7))*8 .. +7]. The gemm then stages W with perfectly linear
// global_load_lds and reads LDS with the same XOR -> bank-conflict-free, zero VALU.
__global__ __launch_bounds__(256) void indrnn_w2bf(
    const float* __restrict__ W, ushort* __restrict__ Wbf)
{
  const int g   = blockIdx.x * 256 + threadIdx.x;   // 8192 slots total
  const int kc  = g >> 11;
  const int rem = g & 2047;
  const int row = rem >> 3;
  const int sp  = rem & 7;
  const int slog = sp ^ (row & 7);
  const float* src = W + row * 256 + kc * 64 + slog * 8;
  const float4 f0 = *(const float4*)src;
  const float4 f1 = *(const float4*)(src + 4);
  uint4 o;
  o.x = pkbf2(f0.x, f0.y); o.y = pkbf2(f0.z, f0.w);
  o.z = pkbf2(f1.x, f1.y); o.w = pkbf2(f1.z, f1.w);
  *(uint4*)(Wbf + (size_t)g * 8) = o;
}

// ---------------- Phase 1: xW[m,h] = sum_i x[m,i] * W[h,i], bf16 MFMA ----------------
// v3: DMA-staged (global_load_lds), VALU-free staging, 3 blocks/CU.
//   BM=64, BN=256 (full H), BK=64; 4 waves, wave = 64 rows x 64 cols.
//   A staged raw fp32 w/ XOR-swizzled source (slot ^= row&7), converted at frag read
//   via v_cvt_pk_bf16_f32. W staged from pre-swizzled bf16 (indrnn_w2bf), linear DMA.
__global__ __launch_bounds__(256, 3) void indrnn_gemm(
    const float* __restrict__ A,
    const ushort* __restrict__ Wbf,
    ushort* __restrict__ C)
{
  __shared__ __align__(16) float  Af[4096];    // 64 rows x 16 slots x 4 fp32 = 16 KB
  __shared__ __align__(16) ushort Bs[16384];   // 256 rows x 8 slots x 8 bf16 = 32 KB

  const int tid   = threadIdx.x;
  const int lane  = tid & 63;
  const int wn    = tid >> 6;      // 0..3 -> 64-col slice of H
  const int l15   = lane & 15;
  const int lhi   = lane >> 4;     // 0..3
  const int m0    = blockIdx.x * 64;
  const int bflat = tid & 192;     // wave base slot within block round

  v4f acc[4][4] = {};

  for (int kc = 0; kc < 4; ++kc) {
    if (kc) __syncthreads();       // all waves done reading previous tiles

    // A tile DMA: 64 rows x 64 k fp32, source pre-swizzled so LDS is XOR-laid-out
    #pragma unroll
    for (int j = 0; j < 4; ++j) {
      const int bf_ = j * 256 + bflat;          // wave-uniform LDS slot base
      const int fl  = bf_ + lane;
      const int row = fl >> 4;
      const int sl  = fl & 15;
      const float* src = A + ((size_t)(m0 + row) << 8) + kc * 64 + ((sl ^ (row & 7)) << 2);
      __builtin_amdgcn_global_load_lds(src, &Af[bf_ << 2], 16, 0, 0);
    }
    // W tile DMA: 256 rows x 64 k bf16, fully linear from pre-swizzled Wbf
    #pragma unroll
    for (int j = 0; j < 8; ++j) {
      const int bf_ = j * 256 + bflat;
      const int fl  = bf_ + lane;
      __builtin_amdgcn_global_load_lds(
          (const float*)(Wbf + (size_t)kc * 16384 + (size_t)fl * 8),
          (float*)(Bs + (size_t)bf_ * 8), 16, 0, 0);
    }
    asm volatile("s_waitcnt vmcnt(0)" ::: "memory");
    __syncthreads();

    #pragma unroll
    for (int kk = 0; kk < 2; ++kk) {
      // B frags: one swizzled 16B slot each (bf16 direct)
      v8s bfr[4];
      #pragma unroll
      for (int nt = 0; nt < 4; ++nt) {
        const int row = wn * 64 + nt * 16 + l15;
        const int sp  = (kk * 4 + lhi) ^ (row & 7);
        bfr[nt] = *(const v8s*)((const char*)Bs + row * 128 + sp * 16);
      }
      // A frags: two swizzled fp32 slots -> cvt_pk -> bf16 frag, then 4 MFMAs
      #pragma unroll
      for (int mt = 0; mt < 4; ++mt) {
        const int row = mt * 16 + l15;
        const int s0  = kk * 8 + lhi * 2;
        const char* base = (const char*)Af + row * 256;
        const float4 lo = *(const float4*)(base + ((s0 ^ (row & 7)) << 4));
        const float4 hi = *(const float4*)(base + (((s0 + 1) ^ (row & 7)) << 4));
        frag_u t;
        t.u[0] = pkbf2(lo.x, lo.y); t.u[1] = pkbf2(lo.z, lo.w);
        t.u[2] = pkbf2(hi.x, hi.y); t.u[3] = pkbf2(hi.z, hi.w);
        #pragma unroll
        for (int nt = 0; nt < 4; ++nt)
          acc[mt][nt] = __builtin_amdgcn_mfma_f32_16x16x32_bf16(t.s, bfr[nt], acc[mt][nt], 0, 0, 0);
      }
    }
  }

  // epilogue: C/D layout col=lane&15, row=(lane>>4)*4+reg
  #pragma unroll
  for (int mt = 0; mt < 4; ++mt) {
    #pragma unroll
    for (int nt = 0; nt < 4; ++nt) {
      #pragma unroll
      for (int r = 0; r < 4; ++r) {
        int row = m0 + mt * 16 + lhi * 4 + r;
        int col = wn * 64 + nt * 16 + l15;
        C[((size_t)row << 8) + col] = f2bf(acc[mt][nt][r]);
      }
    }
  }
}

// ---------------- Phase 2a: per-segment transfer functions ----------------
// IndRNN step f(h)=max(0, x + w*h) preserves the family F(h)=clamp(p*h+a, lo, hi).
// Compose 128 steps per (seg, ch); write (p,a,lo,hi). 1024 blocks -> 16 waves/CU.
__global__ __launch_bounds__(256) void indrnn_seg(
    const ushort* __restrict__ xw,
    const float* __restrict__ w_hh,
    float4* __restrict__ fn)
{
  const int chgrp = blockIdx.x & 63;
  const int seg   = blockIdx.x >> 6;
  const int ch    = chgrp * 256 + threadIdx.x;
  const float w   = w_hh[ch & 255];
  const ushort* px = xw + (size_t)seg * SEGT * BH + ch;

  float p = 1.0f, a = 0.0f, lo = -3.402823466e38f, hi = 3.402823466e38f;

  uint b0[16], b1[16];
  auto ldb = [&](uint (&buf)[16], int kb) {
    const ushort* q = px + (size_t)kb * 16 * BH;
    #pragma unroll
    for (int j = 0; j < 16; ++j) buf[j] = q[(size_t)j * BH];
  };
  auto comp = [&](uint (&buf)[16]) {
    #pragma unroll
    for (int j = 0; j < 16; ++j) {
      float xv = __uint_as_float(buf[j] << 16);
      float A = fmaf(w, lo, xv);
      float B = fmaf(w, hi, xv);
      lo = fmaxf(0.0f, fminf(A, B));
      hi = fmaxf(0.0f, fmaxf(A, B));
      a  = fmaf(w, a, xv);
      p *= w;
    }
  };

  ldb(b0, 0); ldb(b1, 1);
  for (int kb = 0; kb < 8; kb += 2) {
    comp(b0); if (kb + 2 < 8) ldb(b0, kb + 2);
    comp(b1); if (kb + 3 < 8) ldb(b1, kb + 3);
  }
  fn[(size_t)seg * BH + ch] = make_float4(p, a, lo, hi);
}

// ---------------- Phase 2b: prefix-compose h_in, then re-scan + store ----------------
__global__ __launch_bounds__(256) void indrnn_fix(
    const ushort* __restrict__ xw,
    const float* __restrict__ h0,
    const float* __restrict__ w_hh,
    const float4* __restrict__ fn,
    float* __restrict__ out)
{
  const int chgrp = blockIdx.x & 63;
  const int seg   = blockIdx.x >> 6;
  const int ch    = chgrp * 256 + threadIdx.x;
  const float w   = w_hh[ch & 255];

  // exact segment-entry state via <=15 clamp-affine compositions (wave-uniform bound)
  float h = h0[ch];
  for (int s = 0; s < seg; ++s) {
    const float4 F = fn[(size_t)s * BH + ch];
    h = fminf(fmaxf(fmaf(F.x, h, F.y), F.z), F.w);
  }

  const ushort* px = xw + (size_t)seg * SEGT * BH + ch;
  float*        po = out + (size_t)seg * SEGT * BH + ch;

  uint b0[16], b1[16];
  auto ldb = [&](uint (&buf)[16], int kb) {
    const ushort* q = px + (size_t)kb * 16 * BH;
    #pragma unroll
    for (int j = 0; j < 16; ++j) buf[j] = q[(size_t)j * BH];
  };
  auto cp = [&](uint (&buf)[16], int kb) {
    float* o = po + (size_t)kb * 16 * BH;
    #pragma unroll
    for (int j = 0; j < 16; ++j) {
      float xv = __uint_as_float(buf[j] << 16);
      h = fmaxf(fmaf(h, w, xv), 0.0f);
      o[(size_t)j * BH] = h;
    }
  };

  ldb(b0, 0); ldb(b1, 1);
  for (int kb = 0; kb < 8; kb += 2) {
    cp(b0, kb);     if (kb + 2 < 8) ldb(b0, kb + 2);
    cp(b1, kb + 1); if (kb + 3 < 8) ldb(b1, kb + 3);
  }

  if (seg == SEG - 1) out[(size_t)TBH + ch] = h;
}

// ---------------- Fallbacks (workspace-tight path): r0 gemm + r3 scan ----------------
__global__ __launch_bounds__(512) void indrnn_gemm_fb(
    const float* __restrict__ A,
    const float* __restrict__ W,
    ushort* __restrict__ C)
{
  __shared__ ushort As[128 * 72];
  __shared__ ushort Bs[256 * 72];

  const int tid  = threadIdx.x;
  const int lane = tid & 63;
  const int wid  = tid >> 6;
  const int wm   = wid >> 2;
  const int wn   = wid & 3;
  const int m0   = blockIdx.x * 128;
  const int l15 = lane & 15;
  const int lhi = lane >> 4;

  v4f acc[4][4] = {};

  for (int kc = 0; kc < 4; ++kc) {
    #pragma unroll
    for (int j = 0; j < 4; ++j) {
      int f    = j * 512 + tid;
      int row  = f >> 4;
      int colf = f & 15;
      const float4 a4 = *(const float4*)(A + ((size_t)(m0 + row) << 8) + kc * 64 + colf * 4);
      ushort4 b4 = make_ushort4(f2bf(a4.x), f2bf(a4.y), f2bf(a4.z), f2bf(a4.w));
      *(ushort4*)(As + row * 72 + colf * 4) = b4;
    }
    #pragma unroll
    for (int j = 0; j < 8; ++j) {
      int f    = j * 512 + tid;
      int row  = f >> 4;
      int colf = f & 15;
      const float4 a4 = *(const float4*)(W + ((size_t)row << 8) + kc * 64 + colf * 4);
      ushort4 b4 = make_ushort4(f2bf(a4.x), f2bf(a4.y), f2bf(a4.z), f2bf(a4.w));
      *(ushort4*)(Bs + row * 72 + colf * 4) = b4;
    }
    __syncthreads();

    #pragma unroll
    for (int kk = 0; kk < 2; ++kk) {
      const int koff = kk * 32 + lhi * 8;
      v8s af[4], bf[4];
      #pragma unroll
      for (int mt = 0; mt < 4; ++mt)
        af[mt] = *(const v8s*)(As + (wm * 64 + mt * 16 + l15) * 72 + koff);
      #pragma unroll
      for (int nt = 0; nt < 4; ++nt)
        bf[nt] = *(const v8s*)(Bs + (wn * 64 + nt * 16 + l15) * 72 + koff);
      #pragma unroll
      for (int mt = 0; mt < 4; ++mt)
        #pragma unroll
        for (int nt = 0; nt < 4; ++nt)
          acc[mt][nt] = __builtin_amdgcn_mfma_f32_16x16x32_bf16(af[mt], bf[nt], acc[mt][nt], 0, 0, 0);
    }
    __syncthreads();
  }

  #pragma unroll
  for (int mt = 0; mt < 4; ++mt)
    #pragma unroll
    for (int nt = 0; nt < 4; ++nt)
      #pragma unroll
      for (int r = 0; r < 4; ++r) {
        int row = m0 + wm * 64 + mt * 16 + lhi * 4 + r;
        int col = wn * 64 + nt * 16 + l15;
        C[((size_t)row << 8) + col] = f2bf(acc[mt][nt][r]);
      }
}

__global__ __launch_bounds__(128) void indrnn_scan(
    const ushort* __restrict__ xw,
    const float* __restrict__ h0,
    const float* __restrict__ w_hh,
    float* __restrict__ out)
{
  __shared__ __align__(16) ushort tile[3][SCAN_TILE * 64];

  const int lane = threadIdx.x & 63;
  const int wv   = threadIdx.x >> 6;
  const int ch0  = blockIdx.x * 64;
  const int ch   = ch0 + lane;

  const size_t psrc0 = (size_t)(lane >> 3) * BH + (size_t)ch0 + ((lane & 7) << 3);

  auto stage = [&](int ti) {
    const ushort* src = xw + (size_t)ti * SCAN_TILE * BH + psrc0;
    ushort* dst = &tile[ti % 3][0];
    #pragma unroll
    for (int j = 0; j < 16; ++j) {
      __builtin_amdgcn_global_load_lds(
          (const float*)(src + (size_t)j * 8 * BH),
          (float*)(dst + j * 512), 16, 0, 0);
    }
  };

  float h = 0.0f, w = 0.0f;
  if (wv == 0) {
    h = h0[ch];
    w = w_hh[ch & 255];
  } else {
    stage(0);
    stage(1);
    asm volatile("s_waitcnt vmcnt(16)" ::: "memory");
  }
  asm volatile("" ::: "memory");
  __builtin_amdgcn_s_barrier();
  __builtin_amdgcn_sched_barrier(0);

  for (int i = 0; i < NTILE; ++i) {
    if (wv == 0) {
      const ushort* tp = &tile[i % 3][lane];
      float* po = out + (size_t)i * SCAN_TILE * BH + ch;
      #pragma unroll
      for (int t = 0; t < SCAN_TILE; t += 16) {
        ushort v[16];
        #pragma unroll
        for (int j = 0; j < 16; ++j) v[j] = tp[(t + j) * 64];
        #pragma unroll
        for (int j = 0; j < 16; ++j) {
          float xv = __uint_as_float((uint)v[j] << 16);
          h = fmaxf(fmaf(h, w, xv), 0.0f);
          po[(size_t)(t + j) * BH] = h;
        }
      }
    } else {
      if (i + 2 < NTILE) {
        stage(i + 2);
        asm volatile("s_waitcnt vmcnt(16)" ::: "memory");
      } else {
        asm volatile("s_waitcnt vmcnt(0)" ::: "memory");
      }
    }
    asm volatile("" ::: "memory");
    __builtin_amdgcn_s_barrier();
    __builtin_amdgcn_sched_barrier(0);
  }

  if (wv == 0) out[(size_t)TBH + ch] = h;
}

extern "C" void kernel_launch(void* const* d_in, const int* in_sizes, int n_in,
                              void* d_out, int out_size, void* d_ws, size_t ws_size,
                              hipStream_t stream) {
  const float* x    = (const float*)d_in[0];   // [2048, 64, 256]
  const float* h0   = (const float*)d_in[1];   // [1, 64, 256]
  const float* W_ih = (const float*)d_in[2];   // [256, 256]
  const float* w_hh = (const float*)d_in[3];   // [256]
  float* out = (float*)d_out;                  // [T,B,H] ++ [1,B,H]
  ushort* xw = (ushort*)d_ws;                  // bf16 intermediate, 64 MiB

  const size_t off_fn = 64ull << 20;                                  // 64 MiB
  const size_t off_wb = off_fn + (size_t)SEG * BH * sizeof(float4);   // +4 MiB
  const size_t need   = off_wb + 131072;                              // +128 KiB

  if (ws_size >= need) {
    float4* fn  = (float4*)((char*)d_ws + off_fn);
    ushort* wbf = (ushort*)((char*)d_ws + off_wb);
    indrnn_w2bf<<<dim3(32),   dim3(256), 0, stream>>>(W_ih, wbf);
    indrnn_gemm<<<dim3(2048), dim3(256), 0, stream>>>(x, wbf, xw);
    indrnn_seg <<<dim3(1024), dim3(256), 0, stream>>>(xw, w_hh, fn);
    indrnn_fix <<<dim3(1024), dim3(256), 0, stream>>>(xw, h0, w_hh, fn, out);
  } else {
    indrnn_gemm_fb<<<dim3(1024), dim3(512), 0, stream>>>(x, W_ih, xw);
    indrnn_scan<<<dim3(256), dim3(128), 0, stream>>>(xw, h0, w_hh, out);
  }
}